// Round 4
// baseline (68.991 us; speedup 1.0000x reference)
//
#include <hip/hip_runtime.h>

#define BB    131072
#define NLA   20
#define NITC  10
#define STEPS 20
#define DEPTH 4   // steps of noise prefetch held in registers

// Izhikevich: LA=RS(0.02,0.2,-65,8)  ITC=FS(0.10,0.2,-65,2)  CeA=IB(0.02,0.2,-55,4)
// W_la_cea/W_la_itc/W_itc_cea are jnp.full -> uniform rows -> one representative
// ITC and CeA neuron (bit-exact; absmax 0.0 in rounds 1-3).
//
// Memory plan: NO LDS. Each thread's 20 noise floats/step are contiguous and
// 16B-aligned (b*80B), so 5x global_load_dwordx4 -> VGPRs. buf[4][5] gives a
// 4-step-deep register pipeline; use of buf[q] is exactly 15 loads younger
// than its reload, so the compiler's waitcnt pass emits counted vmcnt waits
// (never a full drain). No barriers anywhere; waves drift freely.

__global__ __launch_bounds__(256) void amyg_kernel(
    const float* __restrict__ enemy_pixels,
    const float* __restrict__ pred_dist,
    const float* __restrict__ stress_in,
    const float* __restrict__ pred_facing,
    const float* __restrict__ W_sensory,   // [NLA][4]
    const float* __restrict__ W_la_cea,    // uniform 0.5
    const float* __restrict__ W_la_itc,    // uniform 0.2
    const float* __restrict__ W_itc_cea,   // uniform -0.3
    const float* __restrict__ noise,       // [STEPS][BB][NLA]
    float* __restrict__ out)               // [BB]
{
#pragma clang fp contract(off)
    const int tid = threadIdx.x;
    const int b   = blockIdx.x * 256 + tid;

    const float w_itc = W_la_itc[0];    // 0.2
    const float w_cea = W_la_cea[0];    // 0.5
    const float w_ic  = W_itc_cea[0];   // -0.3

    const float ep = enemy_pixels[b];
    const float pd = pred_dist[b];
    const float st = stress_in[b];
    const float pf = pred_facing[b];

    const float retinal   = fminf(1.0f, ep * 0.08f);
    const float proximity = fmaxf(0.0f, 1.0f - pd / 200.0f);
    const float gaze      = pf * proximity;

    float Ila[NLA];
#pragma unroll
    for (int j = 0; j < NLA; ++j) {
        float acc = retinal * W_sensory[j * 4 + 0];
        acc = acc + proximity * W_sensory[j * 4 + 1];
        acc = acc + st        * W_sensory[j * 4 + 2];
        acc = acc + gaze      * W_sensory[j * 4 + 3];
        Ila[j] = acc * 20.0f;
    }

    float v1[NLA], u1[NLA], r1[NLA];
#pragma unroll
    for (int j = 0; j < NLA; ++j) { v1[j] = -65.0f; u1[j] = 0.2f * -65.0f; r1[j] = 0.0f; }
    float v2 = -65.0f, u2 = 0.2f * -65.0f, r2 = 0.0f;
    float v3 = -65.0f, u3 = 0.2f * -65.0f;
    float accCea = 0.0f;

    // Per-thread noise base: thread b's row, step stride BB*NLA floats.
    const float4* nb4 = (const float4*)(noise + (size_t)b * NLA);
    const size_t  S4  = (size_t)BB * NLA / 4;    // float4s per step

    float4 buf[DEPTH][5];
#pragma unroll
    for (int p = 0; p < DEPTH; ++p)
#pragma unroll
        for (int i = 0; i < 5; ++i)
            buf[p][i] = nb4[(size_t)p * S4 + i];

    auto stepf = [&](float4 (&nb)[5], int s_next) {
        // Unpack (SROA -> pure register aliases, no movs)
        float nz[NLA];
#pragma unroll
        for (int i = 0; i < 5; ++i) {
            nz[4 * i + 0] = nb[i].x; nz[4 * i + 1] = nb[i].y;
            nz[4 * i + 2] = nb[i].z; nz[4 * i + 3] = nb[i].w;
        }

        // ---- LA (RS): consumes all of nb ----
#pragma unroll
        for (int j = 0; j < NLA; ++j) {
            const float I = Ila[j] + nz[j];
            float v = v1[j], u = u1[j];
            v = v + 0.5f * (((((0.04f * v) * v + 5.0f * v) + 140.0f) - u) + I);
            v = v + 0.5f * (((((0.04f * v) * v + 5.0f * v) + 140.0f) - u) + I);
            u = u + 0.02f * (0.2f * v - u);
            const float sp = (v >= 30.0f) ? 1.0f : 0.0f;
            if (v >= 30.0f) v = -65.0f;
            u = u + sp * 8.0f;
            r1[j] = 0.9f * r1[j] + 0.1f * sp;
            v1[j] = v; u1[j] = u;
        }

        // ---- Reload this buffer with step s_next (uniform branch) ----
        if (s_next < STEPS) {
            const float4* src = nb4 + (size_t)s_next * S4;
#pragma unroll
            for (int i = 0; i < 5; ++i) nb[i] = src[i];
        }

        // ---- dots (sequential MAD order == reference) ----
        float d_itc = 0.0f, d_cea = 0.0f;
#pragma unroll
        for (int j = 0; j < NLA; ++j) {
            d_itc = d_itc + r1[j] * w_itc;
            d_cea = d_cea + r1[j] * w_cea;
        }

        // ---- ITC (FS) ----
        {
            const float I = d_itc * 15.0f;
            float v = v2, u = u2;
            v = v + 0.5f * (((((0.04f * v) * v + 5.0f * v) + 140.0f) - u) + I);
            v = v + 0.5f * (((((0.04f * v) * v + 5.0f * v) + 140.0f) - u) + I);
            u = u + 0.10f * (0.2f * v - u);
            const float sp = (v >= 30.0f) ? 1.0f : 0.0f;
            if (v >= 30.0f) v = -65.0f;
            u = u + sp * 2.0f;
            r2 = 0.9f * r2 + 0.1f * sp;
            v2 = v; u2 = u;
        }

        // ---- CeA (IB) ----
        {
            float a2 = 0.0f;
#pragma unroll
            for (int j = 0; j < NITC; ++j) a2 = a2 + r2 * w_ic;
            const float I = d_cea * 20.0f + a2 * 15.0f;
            float v = v3, u = u3;
            v = v + 0.5f * (((((0.04f * v) * v + 5.0f * v) + 140.0f) - u) + I);
            v = v + 0.5f * (((((0.04f * v) * v + 5.0f * v) + 140.0f) - u) + I);
            u = u + 0.02f * (0.2f * v - u);
            const float sp = (v >= 30.0f) ? 1.0f : 0.0f;
            if (v >= 30.0f) v = -55.0f;
            u = u + sp * 4.0f;
            v3 = v; u3 = u;
            accCea = accCea + sp;
        }
    };

    // 5 rolled iterations x 4 static quarters. Last iteration's reloads are
    // skipped by the uniform s_next guard.
#pragma clang loop unroll(disable)
    for (int t = 0; t < STEPS; t += DEPTH) {
        stepf(buf[0], t + 0 + DEPTH);
        stepf(buf[1], t + 1 + DEPTH);
        stepf(buf[2], t + 2 + DEPTH);
        stepf(buf[3], t + 3 + DEPTH);
    }

    // Epilogue: mean of 20 identical integer counts == accCea; / SUBSTEPS.
    const float cea_rate = accCea * 0.5f;
    const float raw = fmaxf(cea_rate, fmaxf(retinal * 0.5f, proximity * 0.3f));
    const bool  nd  = (proximity > 0.9f) && (pf > 0.5f);
    const float fb  = nd ? 0.03f : 0.0f;
    const float threat = (raw > 0.0f) ? (0.6f * raw) : fmaxf(fb * 0.3f, 0.0f);
    out[b] = threat;
}

extern "C" void kernel_launch(void* const* d_in, const int* in_sizes, int n_in,
                              void* d_out, int out_size, void* d_ws, size_t ws_size,
                              hipStream_t stream) {
    const float* enemy_pixels = (const float*)d_in[0];
    const float* pred_dist    = (const float*)d_in[1];
    const float* stress_in    = (const float*)d_in[2];
    const float* pred_facing  = (const float*)d_in[3];
    const float* W_sensory    = (const float*)d_in[4];
    const float* W_la_cea     = (const float*)d_in[5];
    const float* W_la_itc     = (const float*)d_in[6];
    const float* W_itc_cea    = (const float*)d_in[7];
    const float* noise        = (const float*)d_in[8];
    float* out = (float*)d_out;

    amyg_kernel<<<BB / 256, 256, 0, stream>>>(
        enemy_pixels, pred_dist, stress_in, pred_facing,
        W_sensory, W_la_cea, W_la_itc, W_itc_cea, noise, out);
}

// Round 5
// 61.121 us; speedup vs baseline: 1.1288x; 1.1288x over previous
//
#include <hip/hip_runtime.h>

#define BB    131072
#define NLA   20
#define NITC  10
#define STEPS 20
#define NOWN  10   // LA neurons owned per lane (2 lanes per env)

// Izhikevich: LA=RS(0.02,0.2,-65,8)  ITC=FS(0.10,0.2,-65,2)  CeA=IB(0.02,0.2,-55,4)
// W_la_cea/W_la_itc/W_itc_cea are jnp.full -> uniform rows -> one representative
// ITC and CeA neuron (bit-exact; absmax 0.0 rounds 1-4).
//
// Mapping: 2 lanes per env (lane q owns LA neurons [10q,10q+10)) -> 262144
// threads = 4 waves/SIMD (2x round-4 occupancy). Dots gather the partner's
// r1 via __shfl_xor(.,1) (DPP quad-perm, no LDS pipe). Lane 0 accumulates in
// EXACT reference order (own 0..9 then partner 10..19, sequential MADs) and
// is the only lane whose ITC/CeA state reaches out[]; lane 1's copy is dead.
// No LDS, no barriers; depth-2 register prefetch of noise.

__global__ __launch_bounds__(256) void amyg_kernel(
    const float* __restrict__ enemy_pixels,
    const float* __restrict__ pred_dist,
    const float* __restrict__ stress_in,
    const float* __restrict__ pred_facing,
    const float* __restrict__ W_sensory,   // [NLA][4]
    const float* __restrict__ W_la_cea,    // uniform 0.5
    const float* __restrict__ W_la_itc,    // uniform 0.2
    const float* __restrict__ W_itc_cea,   // uniform -0.3
    const float* __restrict__ noise,       // [STEPS][BB][NLA]
    float* __restrict__ out)               // [BB]
{
#pragma clang fp contract(off)
    const int tid = threadIdx.x;
    const int g   = blockIdx.x * 256 + tid;
    const int env = g >> 1;
    const int q   = g & 1;

    const float w_itc = W_la_itc[0];    // 0.2
    const float w_cea = W_la_cea[0];    // 0.5
    const float w_ic  = W_itc_cea[0];   // -0.3

    const float ep = enemy_pixels[env];
    const float pd = pred_dist[env];
    const float st = stress_in[env];
    const float pf = pred_facing[env];

    const float retinal   = fminf(1.0f, ep * 0.08f);
    const float proximity = fmaxf(0.0f, 1.0f - pd / 200.0f);
    const float gaze      = pf * proximity;

    float Ila[NOWN];
#pragma unroll
    for (int j = 0; j < NOWN; ++j) {
        const int row = q * NOWN + j;
        float acc = retinal * W_sensory[row * 4 + 0];
        acc = acc + proximity * W_sensory[row * 4 + 1];
        acc = acc + st        * W_sensory[row * 4 + 2];
        acc = acc + gaze      * W_sensory[row * 4 + 3];
        Ila[j] = acc * 20.0f;
    }

    float v1[NOWN], u1[NOWN], r1[NOWN];
#pragma unroll
    for (int j = 0; j < NOWN; ++j) { v1[j] = -65.0f; u1[j] = 0.2f * -65.0f; r1[j] = 0.0f; }
    float v2 = -65.0f, u2 = 0.2f * -65.0f, r2 = 0.0f;
    float v3 = -65.0f, u3 = 0.2f * -65.0f;
    float accCea = 0.0f;

    // Per-lane noise base: 10 contiguous floats (8B-aligned: 80*env + 40*q).
    const float* nb = noise + (size_t)env * NLA + q * NOWN;
    const size_t S  = (size_t)BB * NLA;    // floats per step

    float buf0[NOWN], buf1[NOWN];
#pragma unroll
    for (int i = 0; i < NOWN; ++i) buf0[i] = nb[i];
#pragma unroll
    for (int i = 0; i < NOWN; ++i) buf1[i] = nb[S + i];

    auto stepf = [&](float (&nz)[NOWN], int s_next) {
        // ---- LA (RS): own 10 neurons ----
#pragma unroll
        for (int j = 0; j < NOWN; ++j) {
            const float I = Ila[j] + nz[j];
            float v = v1[j], u = u1[j];
            v = v + 0.5f * (((((0.04f * v) * v + 5.0f * v) + 140.0f) - u) + I);
            v = v + 0.5f * (((((0.04f * v) * v + 5.0f * v) + 140.0f) - u) + I);
            u = u + 0.02f * (0.2f * v - u);
            const float sp = (v >= 30.0f) ? 1.0f : 0.0f;
            if (v >= 30.0f) v = -65.0f;
            u = u + sp * 8.0f;
            r1[j] = 0.9f * r1[j] + 0.1f * sp;
            v1[j] = v; u1[j] = u;
        }

        // ---- Reload this buffer with step s_next (uniform guard) ----
        if (s_next < STEPS) {
            const float* src = nb + (size_t)s_next * S;
#pragma unroll
            for (int i = 0; i < NOWN; ++i) nz[i] = src[i];
        }

        // ---- Dots: lane0 order = j 0..9 (own) then 10..19 (partner) ----
        float d_itc = 0.0f, d_cea = 0.0f;
#pragma unroll
        for (int k = 0; k < NOWN; ++k) {
            d_itc = d_itc + r1[k] * w_itc;
            d_cea = d_cea + r1[k] * w_cea;
        }
#pragma unroll
        for (int k = 0; k < NOWN; ++k) {
            const float rj = __shfl_xor(r1[k], 1);
            d_itc = d_itc + rj * w_itc;
            d_cea = d_cea + rj * w_cea;
        }

        // ---- ITC (FS), replicated; only lane q==0's state is live ----
        {
            const float I = d_itc * 15.0f;
            float v = v2, u = u2;
            v = v + 0.5f * (((((0.04f * v) * v + 5.0f * v) + 140.0f) - u) + I);
            v = v + 0.5f * (((((0.04f * v) * v + 5.0f * v) + 140.0f) - u) + I);
            u = u + 0.10f * (0.2f * v - u);
            const float sp = (v >= 30.0f) ? 1.0f : 0.0f;
            if (v >= 30.0f) v = -65.0f;
            u = u + sp * 2.0f;
            r2 = 0.9f * r2 + 0.1f * sp;
            v2 = v; u2 = u;
        }

        // ---- CeA (IB), replicated ----
        {
            float a2 = 0.0f;
#pragma unroll
            for (int j = 0; j < NITC; ++j) a2 = a2 + r2 * w_ic;
            const float I = d_cea * 20.0f + a2 * 15.0f;
            float v = v3, u = u3;
            v = v + 0.5f * (((((0.04f * v) * v + 5.0f * v) + 140.0f) - u) + I);
            v = v + 0.5f * (((((0.04f * v) * v + 5.0f * v) + 140.0f) - u) + I);
            u = u + 0.02f * (0.2f * v - u);
            const float sp = (v >= 30.0f) ? 1.0f : 0.0f;
            if (v >= 30.0f) v = -55.0f;
            u = u + sp * 4.0f;
            v3 = v; u3 = u;
            accCea = accCea + sp;
        }
    };

#pragma clang loop unroll(disable)
    for (int t = 0; t < STEPS; t += 2) {
        stepf(buf0, t + 2);
        stepf(buf1, t + 3);
    }

    if (q == 0) {
        const float cea_rate = accCea * 0.5f;   // mean of 20 identical counts / SUBSTEPS
        const float raw = fmaxf(cea_rate, fmaxf(retinal * 0.5f, proximity * 0.3f));
        const bool  nd  = (proximity > 0.9f) && (pf > 0.5f);
        const float fb  = nd ? 0.03f : 0.0f;
        out[env] = (raw > 0.0f) ? (0.6f * raw) : fmaxf(fb * 0.3f, 0.0f);
    }
}

extern "C" void kernel_launch(void* const* d_in, const int* in_sizes, int n_in,
                              void* d_out, int out_size, void* d_ws, size_t ws_size,
                              hipStream_t stream) {
    const float* enemy_pixels = (const float*)d_in[0];
    const float* pred_dist    = (const float*)d_in[1];
    const float* stress_in    = (const float*)d_in[2];
    const float* pred_facing  = (const float*)d_in[3];
    const float* W_sensory    = (const float*)d_in[4];
    const float* W_la_cea     = (const float*)d_in[5];
    const float* W_la_itc     = (const float*)d_in[6];
    const float* W_itc_cea    = (const float*)d_in[7];
    const float* noise        = (const float*)d_in[8];
    float* out = (float*)d_out;

    amyg_kernel<<<(BB * 2) / 256, 256, 0, stream>>>(
        enemy_pixels, pred_dist, stress_in, pred_facing,
        W_sensory, W_la_cea, W_la_itc, W_itc_cea, noise, out);
}

// Round 6
// 49.906 us; speedup vs baseline: 1.3824x; 1.2247x over previous
//
#include <hip/hip_runtime.h>

#define BB    131072
#define NLA   20
#define NITC  10
#define STEPS 20
#define PAD   21   // LDS row stride in floats; gcd(21,32)=1 -> 2 lanes/bank (free)

// Izhikevich: LA=RS(0.02,0.2,-65,8)  ITC=FS(0.10,0.2,-65,2)  CeA=IB(0.02,0.2,-55,4)
// W_la_cea/W_la_itc/W_itc_cea are jnp.full -> uniform rows -> one representative
// ITC and CeA neuron (bit-exact; absmax 0.0 rounds 1-5).
//
// Structure (round-2 dataflow, de-convoyed):
//  - 1 env per thread; per-WAVE double-buffered LDS slab [64][PAD] (wave-
//    synchronous: no __syncthreads anywhere; per-wave in-order queues give
//    ordering).
//  - Per step: 5x coalesced global_load_dwordx4 (1KB/instr) issued 2 steps
//    ahead into regs; reg->LDS publish 1 step ahead; 20 conflict-free scalar
//    ds_reads at stride 21.
//  - Compute body byte-identical to the proven bit-exact kernel.

__global__ __launch_bounds__(256) void amyg_kernel(
    const float* __restrict__ enemy_pixels,
    const float* __restrict__ pred_dist,
    const float* __restrict__ stress_in,
    const float* __restrict__ pred_facing,
    const float* __restrict__ W_sensory,   // [NLA][4]
    const float* __restrict__ W_la_cea,    // uniform 0.5
    const float* __restrict__ W_la_itc,    // uniform 0.2
    const float* __restrict__ W_itc_cea,   // uniform -0.3
    const float* __restrict__ noise,       // [STEPS][BB][NLA]
    float* __restrict__ out)               // [BB]
{
#pragma clang fp contract(off)
    __shared__ float noiz[2][4][64 * PAD];   // 43008 B

    const int tid  = threadIdx.x;
    const int lane = tid & 63;
    const int wv   = tid >> 6;
    const int b    = blockIdx.x * 256 + tid;

    const float w_itc = W_la_itc[0];    // 0.2
    const float w_cea = W_la_cea[0];    // 0.5
    const float w_ic  = W_itc_cea[0];   // -0.3

    const float ep = enemy_pixels[b];
    const float pd = pred_dist[b];
    const float st = stress_in[b];
    const float pf = pred_facing[b];

    const float retinal   = fminf(1.0f, ep * 0.08f);
    const float proximity = fmaxf(0.0f, 1.0f - pd / 200.0f);
    const float gaze      = pf * proximity;

    float Ila[NLA];
#pragma unroll
    for (int j = 0; j < NLA; ++j) {
        float acc = retinal * W_sensory[j * 4 + 0];
        acc = acc + proximity * W_sensory[j * 4 + 1];
        acc = acc + st        * W_sensory[j * 4 + 2];
        acc = acc + gaze      * W_sensory[j * 4 + 3];
        Ila[j] = acc * 20.0f;
    }

    float v1[NLA], u1[NLA], r1[NLA];
#pragma unroll
    for (int j = 0; j < NLA; ++j) { v1[j] = -65.0f; u1[j] = 0.2f * -65.0f; r1[j] = 0.0f; }
    float v2 = -65.0f, u2 = 0.2f * -65.0f, r2 = 0.0f;
    float v3 = -65.0f, u3 = 0.2f * -65.0f;
    float accCea = 0.0f;

    // Global source: this wave's 320-float4 slab region per step.
    const float4* src4  = (const float4*)noise;
    const size_t  S4    = (size_t)BB * NLA / 4;                       // float4/step
    const size_t  base4 = (size_t)blockIdx.x * 1280 + wv * 320 + lane;

    float4 bufA[5];

    auto issue = [&](int t) {      // global -> regs (coalesced, 5x dwordx4)
        const float4* p = src4 + (size_t)t * S4 + base4;
#pragma unroll
        for (int i = 0; i < 5; ++i) bufA[i] = p[i * 64];
    };
    auto publish = [&](int t) {    // regs -> padded slab[t&1] (transpose)
        float* slab = &noiz[t & 1][wv][0];
#pragma unroll
        for (int i = 0; i < 5; ++i) {
            const int g  = i * 64 + lane;
            const int e  = g / 5;
            const int e4 = (g % 5) * 4;
            float* d = &slab[e * PAD + e4];
            d[0] = bufA[i].x; d[1] = bufA[i].y; d[2] = bufA[i].z; d[3] = bufA[i].w;
        }
    };

    issue(0);
    publish(0);        // compiler inserts the vmcnt wait
    issue(1);

#pragma clang loop unroll(disable)
    for (int t = 0; t < STEPS; ++t) {
        const float* row = &noiz[t & 1][wv][lane * PAD];   // conflict-free reads

        // Stage-ahead: publish t+1 (regs already ~1 step old), issue t+2.
        if (t + 1 < STEPS) publish(t + 1);
        if (t + 2 < STEPS) issue(t + 2);

        // ---- LA (RS) ----
#pragma unroll
        for (int j = 0; j < NLA; ++j) {
            const float I = Ila[j] + row[j];
            float v = v1[j], u = u1[j];
            v = v + 0.5f * (((((0.04f * v) * v + 5.0f * v) + 140.0f) - u) + I);
            v = v + 0.5f * (((((0.04f * v) * v + 5.0f * v) + 140.0f) - u) + I);
            u = u + 0.02f * (0.2f * v - u);
            const float sp = (v >= 30.0f) ? 1.0f : 0.0f;
            if (v >= 30.0f) v = -65.0f;
            u = u + sp * 8.0f;
            r1[j] = 0.9f * r1[j] + 0.1f * sp;
            v1[j] = v; u1[j] = u;
        }

        // ---- dots (sequential MAD order == reference) ----
        float d_itc = 0.0f, d_cea = 0.0f;
#pragma unroll
        for (int j = 0; j < NLA; ++j) {
            d_itc = d_itc + r1[j] * w_itc;
            d_cea = d_cea + r1[j] * w_cea;
        }

        // ---- ITC (FS) ----
        {
            const float I = d_itc * 15.0f;
            float v = v2, u = u2;
            v = v + 0.5f * (((((0.04f * v) * v + 5.0f * v) + 140.0f) - u) + I);
            v = v + 0.5f * (((((0.04f * v) * v + 5.0f * v) + 140.0f) - u) + I);
            u = u + 0.10f * (0.2f * v - u);
            const float sp = (v >= 30.0f) ? 1.0f : 0.0f;
            if (v >= 30.0f) v = -65.0f;
            u = u + sp * 2.0f;
            r2 = 0.9f * r2 + 0.1f * sp;
            v2 = v; u2 = u;
        }

        // ---- CeA (IB) ----
        {
            float a2 = 0.0f;
#pragma unroll
            for (int j = 0; j < NITC; ++j) a2 = a2 + r2 * w_ic;
            const float I = d_cea * 20.0f + a2 * 15.0f;
            float v = v3, u = u3;
            v = v + 0.5f * (((((0.04f * v) * v + 5.0f * v) + 140.0f) - u) + I);
            v = v + 0.5f * (((((0.04f * v) * v + 5.0f * v) + 140.0f) - u) + I);
            u = u + 0.02f * (0.2f * v - u);
            const float sp = (v >= 30.0f) ? 1.0f : 0.0f;
            if (v >= 30.0f) v = -55.0f;
            u = u + sp * 4.0f;
            v3 = v; u3 = u;
            accCea = accCea + sp;
        }
    }

    // Epilogue: mean of 20 identical integer counts == accCea; / SUBSTEPS.
    const float cea_rate = accCea * 0.5f;
    const float raw = fmaxf(cea_rate, fmaxf(retinal * 0.5f, proximity * 0.3f));
    const bool  nd  = (proximity > 0.9f) && (pf > 0.5f);
    const float fb  = nd ? 0.03f : 0.0f;
    out[b] = (raw > 0.0f) ? (0.6f * raw) : fmaxf(fb * 0.3f, 0.0f);
}

extern "C" void kernel_launch(void* const* d_in, const int* in_sizes, int n_in,
                              void* d_out, int out_size, void* d_ws, size_t ws_size,
                              hipStream_t stream) {
    const float* enemy_pixels = (const float*)d_in[0];
    const float* pred_dist    = (const float*)d_in[1];
    const float* stress_in    = (const float*)d_in[2];
    const float* pred_facing  = (const float*)d_in[3];
    const float* W_sensory    = (const float*)d_in[4];
    const float* W_la_cea     = (const float*)d_in[5];
    const float* W_la_itc     = (const float*)d_in[6];
    const float* W_itc_cea    = (const float*)d_in[7];
    const float* noise        = (const float*)d_in[8];
    float* out = (float*)d_out;

    amyg_kernel<<<BB / 256, 256, 0, stream>>>(
        enemy_pixels, pred_dist, stress_in, pred_facing,
        W_sensory, W_la_cea, W_la_itc, W_itc_cea, noise, out);
}

// Round 7
// 49.888 us; speedup vs baseline: 1.3829x; 1.0003x over previous
//
#include <hip/hip_runtime.h>

#define BB    131072
#define NLA   20
#define NPAIR 10
#define NITC  10
#define STEPS 20
#define PAD   21   // LDS row stride in floats; gcd(21,32)=1 -> 2 lanes/bank (free)

typedef __attribute__((ext_vector_type(2))) float f32x2;

// Izhikevich: LA=RS(0.02,0.2,-65,8)  ITC=FS(0.10,0.2,-65,2)  CeA=IB(0.02,0.2,-55,4)
// W_la_cea/W_la_itc/W_itc_cea are jnp.full -> uniform rows -> one representative
// ITC and CeA neuron (bit-exact; absmax 0.0 rounds 1-6).
//
// Round-7 structure:
//  - R6 dataflow: per-wave double-buffered padded LDS slab, no barriers,
//    coalesced dwordx4 staging ~2.5 steps ahead.
//  - LA neurons processed as float2 pairs (2p,2p+1) -> v_pk_{mul,add}_f32
//    candidates (element-wise IEEE ops, contract off => bit-exact).
//  - Loop body = { dots(t); publish(t+2); issue(t+3); LA(t+1); tail(t) }:
//    the serial ITC/CeA tail of step t is independent of LA(t+1), so the
//    scheduler interleaves them (fills the tail's dep-stall slots).

__global__ __launch_bounds__(256, 2) void amyg_kernel(
    const float* __restrict__ enemy_pixels,
    const float* __restrict__ pred_dist,
    const float* __restrict__ stress_in,
    const float* __restrict__ pred_facing,
    const float* __restrict__ W_sensory,   // [NLA][4]
    const float* __restrict__ W_la_cea,    // uniform 0.5
    const float* __restrict__ W_la_itc,    // uniform 0.2
    const float* __restrict__ W_itc_cea,   // uniform -0.3
    const float* __restrict__ noise,       // [STEPS][BB][NLA]
    float* __restrict__ out)               // [BB]
{
#pragma clang fp contract(off)
    __shared__ float noiz[2][4][64 * PAD];   // 43008 B

    const int tid  = threadIdx.x;
    const int lane = tid & 63;
    const int wv   = tid >> 6;
    const int b    = blockIdx.x * 256 + tid;

    const float w_itc = W_la_itc[0];    // 0.2
    const float w_cea = W_la_cea[0];    // 0.5
    const float w_ic  = W_itc_cea[0];   // -0.3

    const float ep = enemy_pixels[b];
    const float pd = pred_dist[b];
    const float st = stress_in[b];
    const float pf = pred_facing[b];

    const float retinal   = fminf(1.0f, ep * 0.08f);
    const float proximity = fmaxf(0.0f, 1.0f - pd / 200.0f);
    const float gaze      = pf * proximity;

    // Ila per neuron (exact reference op order), packed into pairs.
    f32x2 Ila2[NPAIR];
#pragma unroll
    for (int p = 0; p < NPAIR; ++p) {
        float h[2];
#pragma unroll
        for (int q = 0; q < 2; ++q) {
            const int row = 2 * p + q;
            float acc = retinal * W_sensory[row * 4 + 0];
            acc = acc + proximity * W_sensory[row * 4 + 1];
            acc = acc + st        * W_sensory[row * 4 + 2];
            acc = acc + gaze      * W_sensory[row * 4 + 3];
            h[q] = acc * 20.0f;
        }
        Ila2[p].x = h[0]; Ila2[p].y = h[1];
    }

    f32x2 v1[NPAIR], u1[NPAIR], r1[NPAIR];
#pragma unroll
    for (int p = 0; p < NPAIR; ++p) {
        v1[p] = -65.0f; u1[p] = 0.2f * -65.0f; r1[p] = 0.0f;
    }
    float v2 = -65.0f, u2 = 0.2f * -65.0f, r2 = 0.0f;
    float v3 = -65.0f, u3 = 0.2f * -65.0f;
    float accCea = 0.0f;

    // Global staging: this wave's 320-float4 region per step.
    const float4* src4  = (const float4*)noise;
    const size_t  S4    = (size_t)BB * NLA / 4;
    const size_t  base4 = (size_t)blockIdx.x * 1280 + wv * 320 + lane;

    float4 bufA[5];

    auto issue = [&](int t) {      // global -> regs, coalesced dwordx4
        const float4* p = src4 + (size_t)t * S4 + base4;
#pragma unroll
        for (int i = 0; i < 5; ++i) bufA[i] = p[i * 64];
    };
    auto publish = [&](int t) {    // regs -> padded slab[t&1]
        float* slab = &noiz[t & 1][wv][0];
#pragma unroll
        for (int i = 0; i < 5; ++i) {
            const int g  = i * 64 + lane;
            const int e  = g / 5;
            const int e4 = (g % 5) * 4;
            float* d = &slab[e * PAD + e4];
            d[0] = bufA[i].x; d[1] = bufA[i].y; d[2] = bufA[i].z; d[3] = bufA[i].w;
        }
    };

    // LA update for step t (reads slab[t&1]); float2 pairs.
    auto la = [&](int t) {
        const float* row = &noiz[t & 1][wv][lane * PAD];
#pragma unroll
        for (int p = 0; p < NPAIR; ++p) {
            f32x2 nz;
            nz.x = row[2 * p]; nz.y = row[2 * p + 1];   // -> ds_read2_b32
            const f32x2 I = Ila2[p] + nz;
            f32x2 v = v1[p], u = u1[p];
            v = v + 0.5f * (((((0.04f * v) * v + 5.0f * v) + 140.0f) - u) + I);
            v = v + 0.5f * (((((0.04f * v) * v + 5.0f * v) + 140.0f) - u) + I);
            u = u + 0.02f * (0.2f * v - u);
            f32x2 sp;
            sp.x = (v.x >= 30.0f) ? 1.0f : 0.0f;
            sp.y = (v.y >= 30.0f) ? 1.0f : 0.0f;
            v.x  = (v.x >= 30.0f) ? -65.0f : v.x;
            v.y  = (v.y >= 30.0f) ? -65.0f : v.y;
            u = u + sp * 8.0f;
            r1[p] = 0.9f * r1[p] + 0.1f * sp;
            v1[p] = v; u1[p] = u;
        }
    };

    float d_itc, d_cea;
    auto dots = [&]() {            // exact reference order: j = 0..19 ascending
        float di = 0.0f, dc = 0.0f;
#pragma unroll
        for (int p = 0; p < NPAIR; ++p) {
            di = di + r1[p].x * w_itc;  dc = dc + r1[p].x * w_cea;
            di = di + r1[p].y * w_itc;  dc = dc + r1[p].y * w_cea;
        }
        d_itc = di; d_cea = dc;
    };

    auto tail = [&]() {
        // ---- ITC (FS) ----
        {
            const float I = d_itc * 15.0f;
            float v = v2, u = u2;
            v = v + 0.5f * (((((0.04f * v) * v + 5.0f * v) + 140.0f) - u) + I);
            v = v + 0.5f * (((((0.04f * v) * v + 5.0f * v) + 140.0f) - u) + I);
            u = u + 0.10f * (0.2f * v - u);
            const float sp = (v >= 30.0f) ? 1.0f : 0.0f;
            if (v >= 30.0f) v = -65.0f;
            u = u + sp * 2.0f;
            r2 = 0.9f * r2 + 0.1f * sp;
            v2 = v; u2 = u;
        }
        // ---- CeA (IB) ----
        {
            float a2 = 0.0f;
#pragma unroll
            for (int j = 0; j < NITC; ++j) a2 = a2 + r2 * w_ic;
            const float I = d_cea * 20.0f + a2 * 15.0f;
            float v = v3, u = u3;
            v = v + 0.5f * (((((0.04f * v) * v + 5.0f * v) + 140.0f) - u) + I);
            v = v + 0.5f * (((((0.04f * v) * v + 5.0f * v) + 140.0f) - u) + I);
            u = u + 0.02f * (0.2f * v - u);
            const float sp = (v >= 30.0f) ? 1.0f : 0.0f;
            if (v >= 30.0f) v = -55.0f;
            u = u + sp * 4.0f;
            v3 = v; u3 = u;
            accCea = accCea + sp;
        }
    };

    // Prologue: stage steps 0,1; issue 2; run LA(0).
    issue(0); publish(0);
    issue(1); publish(1);
    issue(2);
    la(0);

    // Iter t: dots(t) frees r1 -> publish(t+2)/issue(t+3) -> LA(t+1) || tail(t).
#pragma clang loop unroll(disable)
    for (int t = 0; t < STEPS - 1; ++t) {
        dots();
        if (t + 2 < STEPS) publish(t + 2);
        if (t + 3 < STEPS) issue(t + 3);
        la(t + 1);
        tail();
    }
    dots();
    tail();

    // Epilogue: mean of 20 identical integer counts == accCea; / SUBSTEPS.
    const float cea_rate = accCea * 0.5f;
    const float raw = fmaxf(cea_rate, fmaxf(retinal * 0.5f, proximity * 0.3f));
    const bool  nd  = (proximity > 0.9f) && (pf > 0.5f);
    const float fb  = nd ? 0.03f : 0.0f;
    out[b] = (raw > 0.0f) ? (0.6f * raw) : fmaxf(fb * 0.3f, 0.0f);
}

extern "C" void kernel_launch(void* const* d_in, const int* in_sizes, int n_in,
                              void* d_out, int out_size, void* d_ws, size_t ws_size,
                              hipStream_t stream) {
    const float* enemy_pixels = (const float*)d_in[0];
    const float* pred_dist    = (const float*)d_in[1];
    const float* stress_in    = (const float*)d_in[2];
    const float* pred_facing  = (const float*)d_in[3];
    const float* W_sensory    = (const float*)d_in[4];
    const float* W_la_cea     = (const float*)d_in[5];
    const float* W_la_itc     = (const float*)d_in[6];
    const float* W_itc_cea    = (const float*)d_in[7];
    const float* noise        = (const float*)d_in[8];
    float* out = (float*)d_out;

    amyg_kernel<<<BB / 256, 256, 0, stream>>>(
        enemy_pixels, pred_dist, stress_in, pred_facing,
        W_sensory, W_la_cea, W_la_itc, W_itc_cea, noise, out);
}